// Round 2
// 400.451 us; speedup vs baseline: 1.1095x; 1.1095x over previous
//
#include <hip/hip_runtime.h>

// FDTD 2-step update, float32.
// Fields: E (B,1024,1024), Hx (B,1022,1023), Hy (B,1023,1022), B=8.
// Output: concat along axis1 of (E_n,E_m), (Hx_n,Hx_m), (Hy_n,Hy_m).
//
// v2: (a) batch-per-XCD block swizzle (b = lin&7) so each XCD's private L2
//     keeps the stencil row window -> compulsory HBM traffic only;
//     (b) x4 register blocking per thread with vector loads (halo reuse),
//     scalar fallback on domain edges (threads 0/255 and y-edge rows).

#define KF0 (-11.0f / 12.0f)
#define KF1 (1.5f)
#define KF2 (-0.75f)
#define KF3 (1.0f / 6.0f)
#define KB0 (-1.0f / 6.0f)
#define KB1 (0.75f)
#define KB2 (-1.5f)
#define KB3 (11.0f / 12.0f)

typedef float f4 __attribute__((ext_vector_type(4)));
typedef float f2 __attribute__((ext_vector_type(2)));

__device__ __forceinline__ f4 ld4(const float* p) { f4 v; __builtin_memcpy(&v, p, 16); return v; }
__device__ __forceinline__ f2 ld2(const float* p) { f2 v; __builtin_memcpy(&v, p, 8); return v; }
__device__ __forceinline__ void st4(float* p, f4 v) { __builtin_memcpy(p, &v, 16); }

#define LOAD6(dst, p) do { f4 _a = ld4(p); f2 _b = ld2((p) + 4); \
    (dst)[0]=_a.x; (dst)[1]=_a.y; (dst)[2]=_a.z; (dst)[3]=_a.w; (dst)[4]=_b.x; (dst)[5]=_b.y; } while (0)
#define LOAD4(dst, p) do { f4 _a = ld4(p); \
    (dst)[0]=_a.x; (dst)[1]=_a.y; (dst)[2]=_a.z; (dst)[3]=_a.w; } while (0)

// ---- scalar reference paths (exact copy of v1 logic), used at edges ----

__device__ __forceinline__ float amper_pt(const float* __restrict__ e,
                                          const float* __restrict__ hx,
                                          const float* __restrict__ hy,
                                          int y, int x)
{
    float v = e[y * 1024 + x];
    if ((y >= 2) & (y < 1022) & (x >= 2) & (x < 1022)) {
        const float* r0 = hy + (y - 2) * 1022 + (x - 2);
        const float* r1 = r0 + 1022;
        const float* r2 = r1 + 1022;
        v += 0.5f * ((r0[0] + r0[2])
                     - (r1[0] + r1[1] + r1[2])
                     + (r2[0] + r2[1] + r2[2]));
        const float* q0 = hx + (y - 2) * 1023 + (x - 2);
        const float* q1 = q0 + 1023;
        const float* q2 = q1 + 1023;
        v -= 0.5f * ((q0[0] - q0[1] + q0[2])
                     + (-q1[1] + q1[2])
                     + (q2[0] - q2[1] + q2[2]));
    }
    bool cx = (x >= 1) & (x < 1023);
    if ((y < 1020) & cx) {
        const float* c = hy + y * 1022 + (x - 1);
        v += KF0 * c[0] + KF1 * c[1022] + KF2 * c[2044] + KF3 * c[3066];
    }
    if ((y >= 4) & cx) {
        const float* c = hy + (y - 4) * 1022 + (x - 1);
        v += KB0 * c[0] + KB1 * c[1022] + KB2 * c[2044] + KB3 * c[3066];
    }
    bool cy = (y >= 1) & (y < 1023);
    if (cy & (x < 1020)) {
        const float* r = hx + (y - 1) * 1023 + x;
        v -= KF0 * r[0] + KF1 * r[1] + KF2 * r[2] + KF3 * r[3];
    }
    if (cy & (x >= 4)) {
        const float* r = hx + (y - 1) * 1023 + (x - 4);
        v -= KB0 * r[0] + KB1 * r[1] + KB2 * r[2] + KB3 * r[3];
    }
    return v;
}

__device__ __forceinline__ float far_hx_pt(const float* __restrict__ e,
                                           const float* __restrict__ hxp,
                                           int y, int x)
{
    float v = hxp[y * 1023 + x];
    if ((x >= 1) & (x < 1022)) {
        const float* r0 = e + y * 1024 + (x - 1);
        const float* r1 = r0 + 1024;
        const float* r2 = r1 + 1024;
        v -= 0.5f * ((r0[0] - r0[1] + r0[2])
                     + (-r1[1] + r1[2])
                     + (r2[0] - r2[1] + r2[2]));
    }
    if (x < 1021) {
        const float* r = e + (y + 1) * 1024 + x;
        v -= KF0 * r[0] + KF1 * r[1] + KF2 * r[2] + KF3 * r[3];
    }
    if (x >= 2) {
        const float* r = e + (y + 1) * 1024 + (x - 2);
        v -= KB0 * r[0] + KB1 * r[1] + KB2 * r[2] + KB3 * r[3];
    }
    return v;
}

__device__ __forceinline__ float far_hy_pt(const float* __restrict__ e,
                                           const float* __restrict__ hyp,
                                           int y, int x)
{
    float v = hyp[y * 1022 + x];
    if ((y >= 1) & (y < 1022)) {
        const float* r0 = e + (y - 1) * 1024 + x;
        const float* r1 = r0 + 1024;
        const float* r2 = r1 + 1024;
        v += 0.5f * ((r0[0] + r0[2])
                     - (r1[0] + r1[1] + r1[2])
                     + (r2[0] + r2[1] + r2[2]));
    }
    if (y < 1021) {
        const float* c = e + y * 1024 + (x + 1);
        v += KF0 * c[0] + KF1 * c[1024] + KF2 * c[2048] + KF3 * c[3072];
    }
    if (y >= 2) {
        const float* c = e + (y - 2) * 1024 + (x + 1);
        v += KB0 * c[0] + KB1 * c[1024] + KB2 * c[2048] + KB3 * c[3072];
    }
    return v;
}

// ---- amper: E_n = E + S1 - S2 over (1024,1024). grid (1,1024,8), 256 thr ----

__global__ __launch_bounds__(256) void amper_k(
    const float* __restrict__ E, int sEb,
    const float* __restrict__ Hx, int sHxb,
    const float* __restrict__ Hy, int sHyb,
    float* __restrict__ Eo, int sEob)
{
    // batch-per-XCD swizzle: lin%8 -> batch, lin/8 -> row (nwg = 8192 = 8*1024)
    int lin = blockIdx.y + (blockIdx.z << 10);
    int b = lin & 7;
    int y = lin >> 3;
    int x0 = threadIdx.x << 2;

    const float* e  = E  + (size_t)b * sEb;
    const float* hx = Hx + (size_t)b * sHxb;
    const float* hy = Hy + (size_t)b * sHyb;
    float* eo = Eo + (size_t)b * sEob + y * 1024;

    if ((y >= 4) & (y < 1020) & (x0 >= 4) & (x0 <= 1016)) {
        // all 5 stencil regions active for x' = x0..x0+3
        float cA[6], cB[6], cC[6];              // Hy rows y-2,y-1,y cols x0-2..x0+3
        const float* hyr = hy + (y - 2) * 1022 + (x0 - 2);
        LOAD6(cA, hyr);
        LOAD6(cB, hyr + 1022);
        LOAD6(cC, hyr + 2044);
        float km4[4], km3[4], kp1[4], kp2[4], kp3[4];  // Hy col rows, cols x0-1..x0+2
        const float* hyc = hy + (y - 4) * 1022 + (x0 - 1);
        LOAD4(km4, hyc);
        LOAD4(km3, hyc + 1022);
        LOAD4(kp1, hyc + 5 * 1022);
        LOAD4(kp2, hyc + 6 * 1022);
        LOAD4(kp3, hyc + 7 * 1022);
        float dA[6], dC[6], e12[12];            // Hx rows y-2,y (6 wide); row y-1 cols x0-4..x0+7
        const float* hxr = hx + (y - 2) * 1023 + (x0 - 2);
        LOAD6(dA, hxr);
        LOAD6(dC, hxr + 2046);
        const float* hxm = hx + (y - 1) * 1023 + (x0 - 4);
        LOAD4(&e12[0], hxm);
        LOAD4(&e12[4], hxm + 4);
        LOAD4(&e12[8], hxm + 8);
        f4 ev = ld4(e + y * 1024 + x0);
        f4 o;
        #pragma unroll
        for (int j = 0; j < 4; ++j) {
            float v = ev[j];
            // interior 3x3 (f^T on Hy, f on Hx)
            v += 0.5f * ((cA[j] + cA[j + 2])
                         - (cB[j] + cB[j + 1] + cB[j + 2])
                         + (cC[j] + cC[j + 1] + cC[j + 2]));
            v -= 0.5f * ((dA[j] - dA[j + 1] + dA[j + 2])
                         + (-e12[j + 3] + e12[j + 4])
                         + (dC[j] - dC[j + 1] + dC[j + 2]));
            // KF/KB columns on Hy (col x'-1)
            v += KF0 * cC[j + 1] + KF1 * kp1[j] + KF2 * kp2[j] + KF3 * kp3[j];
            v += KB0 * km4[j] + KB1 * km3[j] + KB2 * cA[j + 1] + KB3 * cB[j + 1];
            // KF/KB rows on Hx (row y-1)
            v -= KF0 * e12[j + 4] + KF1 * e12[j + 5] + KF2 * e12[j + 6] + KF3 * e12[j + 7];
            v -= KB0 * e12[j] + KB1 * e12[j + 1] + KB2 * e12[j + 2] + KB3 * e12[j + 3];
            o[j] = v;
        }
        st4(eo + x0, o);
    } else {
        #pragma unroll
        for (int j = 0; j < 4; ++j)
            eo[x0 + j] = amper_pt(e, hx, hy, y, x0 + j);
    }
}

// ---- faraday: Hx_n (1022,1023), Hy_n (1023,1022). grid (1,1023,8), 256 thr ----

__global__ __launch_bounds__(256) void faraday_k(
    const float* __restrict__ E, int sEb,
    const float* __restrict__ Hx, int sHxb,
    const float* __restrict__ Hy, int sHyb,
    float* __restrict__ Hxo, int sHxob,
    float* __restrict__ Hyo, int sHyob)
{
    // batch-per-XCD swizzle: nwg = 8184 = 8*1023
    int lin = blockIdx.y + 1023 * blockIdx.z;
    int b = lin & 7;
    int y = lin >> 3;                          // 0..1022
    int x0 = threadIdx.x << 2;

    const float* e = E + (size_t)b * sEb;
    bool xfast = (x0 >= 4) & (x0 <= 1016);

    // Hx part: rows 0..1021, cols 0..1022
    if (y < 1022) {
        const float* hxp = Hx + (size_t)b * sHxb;
        float* hxo = Hxo + (size_t)b * sHxob + y * 1023;
        if (xfast) {
            float gA[6], gC[6], h9[9];
            const float* er = e + y * 1024 + (x0 - 1);   // rows y,y+2 cols x0-1..x0+4
            LOAD6(gA, er);
            LOAD6(gC, er + 2048);
            const float* em = e + (y + 1) * 1024 + (x0 - 2);  // row y+1 cols x0-2..x0+6
            LOAD4(&h9[0], em);
            LOAD4(&h9[4], em + 4);
            h9[8] = em[8];
            f4 hv = ld4(hxp + y * 1023 + x0);
            f4 o;
            #pragma unroll
            for (int j = 0; j < 4; ++j) {
                float v = hv[j];
                v -= 0.5f * ((gA[j] - gA[j + 1] + gA[j + 2])
                             + (-h9[j + 2] + h9[j + 3])
                             + (gC[j] - gC[j + 1] + gC[j + 2]));
                v -= KF0 * h9[j + 2] + KF1 * h9[j + 3] + KF2 * h9[j + 4] + KF3 * h9[j + 5];
                v -= KB0 * h9[j] + KB1 * h9[j + 1] + KB2 * h9[j + 2] + KB3 * h9[j + 3];
                o[j] = v;
            }
            st4(hxo + x0, o);
        } else {
            for (int j = 0; j < 4; ++j) {
                int x = x0 + j;
                if (x < 1023) hxo[x] = far_hx_pt(e, hxp, y, x);
            }
        }
    }

    // Hy part: rows 0..1022, cols 0..1021
    {
        const float* hyp = Hy + (size_t)b * sHyb;
        float* hyo = Hyo + (size_t)b * sHyob + y * 1022;
        if (xfast & (y >= 2) & (y <= 1020)) {
            float mA[6], mB[6], mC[6], nA[4], nD[4], nE[4];
            const float* er = e + (y - 1) * 1024 + x0;   // rows y-1,y,y+1 cols x0..x0+5
            LOAD6(mA, er);
            LOAD6(mB, er + 1024);
            LOAD6(mC, er + 2048);
            const float* en = e + (y - 2) * 1024 + (x0 + 1);  // rows y-2,y+2,y+3 cols x0+1..x0+4
            LOAD4(nA, en);
            LOAD4(nD, en + 4 * 1024);
            LOAD4(nE, en + 5 * 1024);
            f4 hv = ld4(hyp + y * 1022 + x0);
            f4 o;
            #pragma unroll
            for (int j = 0; j < 4; ++j) {
                float v = hv[j];
                v += 0.5f * ((mA[j] + mA[j + 2])
                             - (mB[j] + mB[j + 1] + mB[j + 2])
                             + (mC[j] + mC[j + 1] + mC[j + 2]));
                v += KF0 * mB[j + 1] + KF1 * mC[j + 1] + KF2 * nD[j] + KF3 * nE[j];
                v += KB0 * nA[j] + KB1 * mA[j + 1] + KB2 * mB[j + 1] + KB3 * mC[j + 1];
                o[j] = v;
            }
            st4(hyo + x0, o);
        } else {
            for (int j = 0; j < 4; ++j) {
                int x = x0 + j;
                if (x < 1022) hyo[x] = far_hy_pt(e, hyp, y, x);
            }
        }
    }
}

extern "C" void kernel_launch(void* const* d_in, const int* in_sizes, int n_in,
                              void* d_out, int out_size, void* d_ws, size_t ws_size,
                              hipStream_t stream)
{
    const float* E  = (const float*)d_in[0];
    const float* Hx = (const float*)d_in[1];
    const float* Hy = (const float*)d_in[2];

    float* out = (float*)d_out;
    float* Eo  = out;                      // 8 * 2048 * 1024
    float* Hxo = out + 16777216;           // 8 * 2044 * 1023
    float* Hyo = Hxo + 16728096;           // 8 * 2046 * 1022

    const int sE = 1024 * 1024;
    const int sHx = 1022 * 1023;
    const int sHy = 1023 * 1022;
    const int sEo = 2 * 1024 * 1024;
    const int sHo = 2 * 1045506;

    dim3 blk(256, 1, 1);
    dim3 gA(1, 1024, 8);
    dim3 gF(1, 1023, 8);

    // step 1: E_n = amper(E, Hx, Hy)
    amper_k<<<gA, blk, 0, stream>>>(E, sE, Hx, sHx, Hy, sHy, Eo, sEo);
    // step 2: Hx_n, Hy_n = faraday(E_n, Hx, Hy)
    faraday_k<<<gF, blk, 0, stream>>>(Eo, sEo, Hx, sHx, Hy, sHy,
                                      Hxo, sHo, Hyo, sHo);
    // step 3: E_m = amper(E_n, Hx_n, Hy_n)
    amper_k<<<gA, blk, 0, stream>>>(Eo, sEo, Hxo, sHo, Hyo, sHo,
                                    Eo + 1024 * 1024, sEo);
    // step 4: Hx_m, Hy_m = faraday(E_m, Hx_n, Hy_n)
    faraday_k<<<gF, blk, 0, stream>>>(Eo + 1024 * 1024, sEo, Hxo, sHo, Hyo, sHo,
                                      Hxo + 1045506, sHo, Hyo + 1045506, sHo);
}